// Round 18
// baseline (423.391 us; speedup 1.0000x reference)
//
#include <hip/hip_runtime.h>
#include <hip/hip_cooperative_groups.h>
#include <cstddef>
#include <cstdint>

namespace cg = cooperative_groups;

#define NE 2048
#define NX 3
#define NROWS (NE - 1)
#define BS 64
#define BR 192
#define NBLK 32
#define NPAIR 16
#define CWG 120      // cooperative grid size (12 apply + 108 far workers)

// PLANAR convention: within an operator of half-energy-width he, index = x*he + e.
// ws layout (floats):
//   wf   [3*NE]        @ 0
//   acc  [3*NE]        @ 6144
//   Gs16 [128*48*48]               16-energy inverses
//   L1   [64*96*96]                32-energy inverses
//   L2   [32*192*192]              64-energy inverses  (== G for the tail)
//   ops1 [32][3][192*192]          H, J2, J3
//   pr   [16][3][192*192]          P, R2, R3
//   Mtmp [32*96*96]

static __device__ __forceinline__ float dy_of(const float* E) {
    return logf(E[NE - 1] / E[0]) / (float)(NE - 1);
}

#define DOT4(a, b) ((a).x * (b).x + (a).y * (b).y + (a).z * (b).z + (a).w * (b).w)
#define FMA4(acc, s, b) { (acc).x += (s) * (b).x; (acc).y += (s) * (b).y; \
                          (acc).z += (s) * (b).z; (acc).w += (s) * (b).w; }

// Fused boot: bid<8 -> init role; else tinv16. Verified R17.
__global__ __launch_bounds__(256) void k_boot(const float* __restrict__ E,
                                              const float* __restrict__ R,
                                              const float* __restrict__ K,
                                              const float* __restrict__ S0,
                                              const float* __restrict__ SC,
                                              float* __restrict__ out,
                                              float* __restrict__ wf,
                                              float* __restrict__ acc,
                                              float* __restrict__ Gs16) {
    const size_t PL = (size_t)NE * NE;
    int tid = threadIdx.x;
    float dy = dy_of(E);

    if (blockIdx.x < 8) {
        int i = blockIdx.x * 256 + tid;
        if (i >= NE) return;
        float wlast = 0.5f * dy * E[NE - 1];
        float srcl[NX], Fl[NX];
#pragma unroll
        for (int p = 0; p < NX; ++p) srcl[p] = S0[p] / R[p * NE + NE - 1];
#pragma unroll
        for (int x = 0; x < NX; ++x) {
            float s = SC[x * NE + NE - 1];
#pragma unroll
            for (int p = 0; p < NX; ++p)
                s += K[(size_t)(x * NX + p) * PL + (size_t)(NE - 1) * NE + (NE - 1)] * srcl[p];
            Fl[x] = s / R[x * NE + NE - 1];
        }
        out[i] = E[i];
        if (i == NE - 1) {
#pragma unroll
            for (int x = 0; x < NX; ++x) {
                out[(1 + x) * NE + i] = Fl[x] > 0.f ? Fl[x] : 0.f;
                wf[x * NE + i] = wlast * Fl[x];
                acc[x * NE + i] = 0.f;
            }
            return;
        }
#pragma unroll
        for (int x = 0; x < NX; ++x) {
            float s = SC[x * NE + i];
#pragma unroll
            for (int p = 0; p < NX; ++p)
                s += K[(size_t)(x * NX + p) * PL + (size_t)i * NE + (NE - 1)] *
                     (wlast * Fl[p] + srcl[p]);
            acc[x * NE + i] = s;
        }
        return;
    }

    __shared__ float4 Xs4[16][49];
    __shared__ float Kst[16][16][12];
    __shared__ float Binv[16][9];
    __shared__ float wloc[16];
    int sb = blockIdx.x - 8;
    int i0 = sb * 16;

    if (tid < 16) {
        int j = i0 + tid;
        wloc[tid] = (j < NE - 1) ? dy * E[j] : 0.f;
        int i = i0 + tid, ii = tid;
        float b00, b01, b02, b10, b11, b12, b20, b21, b22;
        if (i < NROWS) {
            float h = -0.5f * dy * E[i];
            size_t d = (size_t)i * NE + i;
            b00 = h * K[0 * PL + d] + R[0 * NE + i];
            b01 = h * K[1 * PL + d];
            b02 = h * K[2 * PL + d];
            b10 = h * K[3 * PL + d];
            b11 = h * K[4 * PL + d] + R[1 * NE + i];
            b12 = h * K[5 * PL + d];
            b20 = h * K[6 * PL + d];
            b21 = h * K[7 * PL + d];
            b22 = h * K[8 * PL + d] + R[2 * NE + i];
        } else {
            b00 = 1.f; b01 = 0.f; b02 = 0.f;
            b10 = 0.f; b11 = 1.f; b12 = 0.f;
            b20 = 0.f; b21 = 0.f; b22 = 1.f;
        }
        float C00 = b11 * b22 - b12 * b21;
        float C01 = -(b10 * b22 - b12 * b20);
        float C02 = b10 * b21 - b11 * b20;
        float C10 = -(b01 * b22 - b02 * b21);
        float C11 = b00 * b22 - b02 * b20;
        float C12 = -(b00 * b21 - b01 * b20);
        float C20 = b01 * b12 - b02 * b11;
        float C21 = -(b00 * b12 - b02 * b10);
        float C22 = b00 * b11 - b01 * b10;
        float inv = 1.f / (b00 * C00 + b01 * C01 + b02 * C02);
        Binv[ii][0] = C00 * inv; Binv[ii][1] = C10 * inv; Binv[ii][2] = C20 * inv;
        Binv[ii][3] = C01 * inv; Binv[ii][4] = C11 * inv; Binv[ii][5] = C21 * inv;
        Binv[ii][6] = C02 * inv; Binv[ii][7] = C12 * inv; Binv[ii][8] = C22 * inv;
    }
    __syncthreads();
    for (int q = tid; q < 16 * 16 * 9; q += 256) {
        int jj = q & 15;
        int ii = (q >> 4) & 15;
        int pair = q >> 8;
        Kst[ii][jj][4 * (pair / 3) + (pair % 3)] =
            K[(size_t)pair * PL + (size_t)(i0 + ii) * NE + (i0 + jj)] * wloc[jj];
    }
    __syncthreads();

    int cloc = tid >> 2, sub = tid & 3;
    if (cloc < 48) {
        for (int ii = 15; ii >= 0; --ii) {
            int i = i0 + ii;
            float v0 = 0.f, v1 = 0.f, v2 = 0.f;
            if (sub == 0) {
                v0 = (cloc == 0 * 16 + ii) ? 1.f : 0.f;
                v1 = (cloc == 1 * 16 + ii) ? 1.f : 0.f;
                v2 = (cloc == 2 * 16 + ii) ? 1.f : 0.f;
            }
            if (i < NROWS) {
                for (int jj = ii + 1 + sub; jj < 16; jj += 4) {
                    const float* kp = &Kst[ii][jj][0];
                    float4 k0 = *(const float4*)(kp);
                    float4 k1 = *(const float4*)(kp + 4);
                    float4 k2 = *(const float4*)(kp + 8);
                    float4 xv = Xs4[jj][cloc];
                    v0 += k0.x * xv.x + k0.y * xv.y + k0.z * xv.z;
                    v1 += k1.x * xv.x + k1.y * xv.y + k1.z * xv.z;
                    v2 += k2.x * xv.x + k2.y * xv.y + k2.z * xv.z;
                }
            }
            v0 += __shfl_xor(v0, 1); v0 += __shfl_xor(v0, 2);
            v1 += __shfl_xor(v1, 1); v1 += __shfl_xor(v1, 2);
            v2 += __shfl_xor(v2, 1); v2 += __shfl_xor(v2, 2);
            if (sub == 0) {
                float f0, f1, f2;
                if (i < NROWS) {
                    const float* bv = Binv[ii];
                    f0 = bv[0] * v0 + bv[1] * v1 + bv[2] * v2;
                    f1 = bv[3] * v0 + bv[4] * v1 + bv[5] * v2;
                    f2 = bv[6] * v0 + bv[7] * v1 + bv[8] * v2;
                } else {
                    f0 = v0; f1 = v1; f2 = v2;
                }
                Xs4[ii][cloc] = make_float4(f0, f1, f2, 0.f);
            }
            __builtin_amdgcn_wave_barrier();
        }
    }
    __syncthreads();
    float* Gb = Gs16 + (size_t)sb * 48 * 48;
    for (int t = tid; t < 48 * 48; t += 256) {
        int rp = t / 48, c = t % 48;
        int x = rp >> 4, ii = rp & 15;
        Gb[t] = ((const float*)&Xs4[ii][c])[x];
    }
}

// Merge 16+16 -> 32 (verified). 64 WGs.
__global__ __launch_bounds__(256) void k_merge48(const float* __restrict__ E,
                                                 const float* __restrict__ K,
                                                 const float* __restrict__ Gs16,
                                                 float* __restrict__ G32) {
    __shared__ float Ls[48][49], Bs[48][49], Ks[48][49], Ms[48][49];
    const size_t PL = (size_t)NE * NE;
    int q = blockIdx.x;
    int i0 = q * 32;
    int tid = threadIdx.x;
    float dy = dy_of(E);
    const float* GL = Gs16 + (size_t)(2 * q) * 2304;
    const float* GH = Gs16 + (size_t)(2 * q + 1) * 2304;
    for (int t = tid; t < 2304; t += 256) {
        int r = t / 48, c = t % 48;
        Ls[r][c] = GL[t];
        Bs[r][c] = GH[t];
        int x = r >> 4, ii = r & 15, p = c >> 4, jj = c & 15;
        int j = i0 + 16 + jj;
        float w = (j < NE - 1) ? dy * E[j] : 0.f;
        Ks[r][c] = w * K[(size_t)(x * 3 + p) * PL + (size_t)(i0 + ii) * NE + j];
    }
    __syncthreads();
    int tx = tid & 15, ty = tid >> 4;
    float m[3][3] = {};
    for (int k = 0; k < 48; ++k) {
        float a0 = Ks[ty * 3 + 0][k], a1 = Ks[ty * 3 + 1][k], a2 = Ks[ty * 3 + 2][k];
        float b0 = Bs[k][tx * 3 + 0], b1 = Bs[k][tx * 3 + 1], b2 = Bs[k][tx * 3 + 2];
        m[0][0] += a0 * b0; m[0][1] += a0 * b1; m[0][2] += a0 * b2;
        m[1][0] += a1 * b0; m[1][1] += a1 * b1; m[1][2] += a1 * b2;
        m[2][0] += a2 * b0; m[2][1] += a2 * b1; m[2][2] += a2 * b2;
    }
#pragma unroll
    for (int i = 0; i < 3; ++i)
#pragma unroll
        for (int j = 0; j < 3; ++j) Ms[ty * 3 + i][tx * 3 + j] = m[i][j];
    __syncthreads();
    float cc[3][3] = {};
    for (int k = 0; k < 48; ++k) {
        float a0 = Ls[ty * 3 + 0][k], a1 = Ls[ty * 3 + 1][k], a2 = Ls[ty * 3 + 2][k];
        float b0 = Ms[k][tx * 3 + 0], b1 = Ms[k][tx * 3 + 1], b2 = Ms[k][tx * 3 + 2];
        cc[0][0] += a0 * b0; cc[0][1] += a0 * b1; cc[0][2] += a0 * b2;
        cc[1][0] += a1 * b0; cc[1][1] += a1 * b1; cc[1][2] += a1 * b2;
        cc[2][0] += a2 * b0; cc[2][1] += a2 * b1; cc[2][2] += a2 * b2;
    }
    float* O = G32 + (size_t)q * 96 * 96;
    for (int t = tid; t < 2304; t += 256) {
        int r = t / 48, c = t % 48;
        int x = r >> 4, ii = r & 15, p = c >> 4, jj = c & 15;
        O[(size_t)(x * 32 + ii) * 96 + (p * 32 + jj)] = Ls[r][c];
        O[(size_t)(x * 32 + 16 + ii) * 96 + (p * 32 + 16 + jj)] = Bs[r][c];
        O[(size_t)(x * 32 + 16 + ii) * 96 + (p * 32 + jj)] = 0.f;
    }
#pragma unroll
    for (int i = 0; i < 3; ++i)
#pragma unroll
        for (int j = 0; j < 3; ++j) {
            int r = ty * 3 + i, c = tx * 3 + j;
            int x = r >> 4, ii = r & 15, p = c >> 4, jj = c & 15;
            O[(size_t)(x * 32 + ii) * 96 + (p * 32 + 16 + jj)] = cc[i][j];
        }
}

// LDS-free merge A (he=32, h=96). grid (32,9). Verified R16/R17.
__global__ __launch_bounds__(256) void k_mA32(const float* __restrict__ E,
                                              const float* __restrict__ K,
                                              const float* __restrict__ srcG,
                                              float* __restrict__ M) {
    const size_t PL = (size_t)NE * NE;
    const int h = 96, he = 32;
    int mg = blockIdx.x, tz = blockIdx.y;
    int tr = tz / 3, tc = tz % 3;
    int tid = threadIdx.x;
    int tx = tid & 15, ty = tid >> 4;
    int i0 = mg * 64;
    int row0 = tr * 32 + ty * 2;
    int c0 = tc * 32 + tx * 2;
    float dy = dy_of(E);
    const float* GH = srcG + (size_t)(2 * mg + 1) * h * h;
    int xr = row0 / he, er = row0 % he;
    float2 acc0 = {0, 0}, acc1 = {0, 0};
    for (int k0 = 0; k0 < h; k0 += 4) {
        int p = k0 / he, ek = k0 % he;
        int j0 = i0 + he + ek;
        float w0 = (j0 + 0 < NE - 1) ? dy * E[j0 + 0] : 0.f;
        float w1 = (j0 + 1 < NE - 1) ? dy * E[j0 + 1] : 0.f;
        float w2 = (j0 + 2 < NE - 1) ? dy * E[j0 + 2] : 0.f;
        float w3 = (j0 + 3 < NE - 1) ? dy * E[j0 + 3] : 0.f;
        const float* Kp = K + (size_t)(xr * 3 + p) * PL + (size_t)(i0 + er) * NE + j0;
        float4 a0 = *(const float4*)(Kp);
        float4 a1 = *(const float4*)(Kp + NE);
        a0.x *= w0; a0.y *= w1; a0.z *= w2; a0.w *= w3;
        a1.x *= w0; a1.y *= w1; a1.z *= w2; a1.w *= w3;
        float2 b0 = *(const float2*)(GH + (size_t)(k0 + 0) * h + c0);
        float2 b1 = *(const float2*)(GH + (size_t)(k0 + 1) * h + c0);
        float2 b2 = *(const float2*)(GH + (size_t)(k0 + 2) * h + c0);
        float2 b3 = *(const float2*)(GH + (size_t)(k0 + 3) * h + c0);
        acc0.x += a0.x * b0.x + a0.y * b1.x + a0.z * b2.x + a0.w * b3.x;
        acc0.y += a0.x * b0.y + a0.y * b1.y + a0.z * b2.y + a0.w * b3.y;
        acc1.x += a1.x * b0.x + a1.y * b1.x + a1.z * b2.x + a1.w * b3.x;
        acc1.y += a1.x * b0.y + a1.y * b1.y + a1.z * b2.y + a1.w * b3.y;
    }
    float* Ob = M + (size_t)mg * h * h + (size_t)row0 * h + c0;
    *(float2*)(Ob) = acc0;
    *(float2*)(Ob + h) = acc1;
}

// LDS-free merge B (he=32, n=192). grid (32,36). Verified R16/R17.
__global__ __launch_bounds__(256) void k_mB32(const float* __restrict__ srcG,
                                              const float* __restrict__ M,
                                              float* __restrict__ dst) {
    const int h = 96, n = 192;
    int mg = blockIdx.x, tz = blockIdx.y;
    int tr = tz / 6, tc = tz % 6;
    int tid = threadIdx.x;
    int tx = tid & 15, ty = tid >> 4;
    int row0 = tr * 32 + ty * 2;
    int c0 = tc * 32 + tx * 2;
    const float* GL = srcG + (size_t)(2 * mg) * h * h;
    const float* GH = srcG + (size_t)(2 * mg + 1) * h * h;
    const float* Mb = M + (size_t)mg * h * h;
    float* O = dst + (size_t)mg * n * n;
    int xr = row0 / 64, e2r = row0 % 64;
    int xc = c0 / 64, e2c = c0 % 64;
    bool rtop = e2r < 32, ctop = e2c < 32;
    if (rtop && ctop) {
        const float* S = GL + (size_t)(xr * 32 + e2r) * h + (xc * 32 + e2c);
        *(float2*)(O + (size_t)row0 * n + c0) = *(const float2*)(S);
        *(float2*)(O + (size_t)(row0 + 1) * n + c0) = *(const float2*)(S + h);
    } else if (!rtop && !ctop) {
        const float* S = GH + (size_t)(xr * 32 + e2r - 32) * h + (xc * 32 + e2c - 32);
        *(float2*)(O + (size_t)row0 * n + c0) = *(const float2*)(S);
        *(float2*)(O + (size_t)(row0 + 1) * n + c0) = *(const float2*)(S + h);
    } else if (!rtop && ctop) {
        float2 z = {0, 0};
        *(float2*)(O + (size_t)row0 * n + c0) = z;
        *(float2*)(O + (size_t)(row0 + 1) * n + c0) = z;
    } else {
        const float* Ar = GL + (size_t)(xr * 32 + e2r) * h;
        int cm = xc * 32 + (e2c - 32);
        float2 acc0 = {0, 0}, acc1 = {0, 0};
        for (int k0 = 0; k0 < h; k0 += 4) {
            float4 a0 = *(const float4*)(Ar + k0);
            float4 a1 = *(const float4*)(Ar + h + k0);
            float2 b0 = *(const float2*)(Mb + (size_t)(k0 + 0) * h + cm);
            float2 b1 = *(const float2*)(Mb + (size_t)(k0 + 1) * h + cm);
            float2 b2 = *(const float2*)(Mb + (size_t)(k0 + 2) * h + cm);
            float2 b3 = *(const float2*)(Mb + (size_t)(k0 + 3) * h + cm);
            acc0.x += a0.x * b0.x + a0.y * b1.x + a0.z * b2.x + a0.w * b3.x;
            acc0.y += a0.x * b0.y + a0.y * b1.y + a0.z * b2.y + a0.w * b3.y;
            acc1.x += a1.x * b0.x + a1.y * b1.x + a1.z * b2.x + a1.w * b3.x;
            acc1.y += a1.x * b0.y + a1.y * b1.y + a1.z * b2.y + a1.w * b3.y;
        }
        *(float2*)(O + (size_t)row0 * n + c0) = acc0;
        *(float2*)(O + (size_t)(row0 + 1) * n + c0) = acc1;
    }
}

// ops1[s][t-1] = G[s] @ Kp(s,s+t). grid (32,3,9). Verified R13.
__global__ __launch_bounds__(256) void k_gops1(const float* __restrict__ K,
                                               const float* __restrict__ G,
                                               float* __restrict__ ops1) {
    int s = blockIdx.x, ty_ = blockIdx.y, tz = blockIdx.z;
    int rt = tz / 3, ct = tz % 3;
    int t = ty_ + 1;
    float* O = ops1 + (size_t)(s * 3 + ty_) * BR * BR;
    int tid = threadIdx.x;
    if (s + t > NBLK - 1) {
        for (int q = tid; q < 64 * 64; q += 256)
            O[(size_t)(rt * 64 + q / 64) * BR + ct * 64 + (q % 64)] = 0.f;
        return;
    }
    const size_t PL = (size_t)NE * NE;
    const float* Ga = G + (size_t)s * BR * BR;
    int tgt0 = (s + t) * 64;
    int tx = tid & 15, ty = tid >> 4;
    int row0 = rt * 64 + ty * 4;
    int c0 = tx * 4;
    bool maskLast = (s + t == NBLK - 1) && (tx == 15);
    float4 acc0 = {0, 0, 0, 0}, acc1 = {0, 0, 0, 0};
    float4 acc2 = {0, 0, 0, 0}, acc3 = {0, 0, 0, 0};
    for (int k0 = 0; k0 < BR; k0 += 4) {
        int x = k0 >> 6;
        const float* Bb = K + (size_t)(x * 3 + ct) * PL +
                          (size_t)(s * 64 + (k0 & 63)) * NE + tgt0 + c0;
        float4 b0 = *(const float4*)(Bb);
        float4 b1 = *(const float4*)(Bb + NE);
        float4 b2 = *(const float4*)(Bb + 2 * NE);
        float4 b3 = *(const float4*)(Bb + 3 * NE);
        if (maskLast) { b0.w = 0.f; b1.w = 0.f; b2.w = 0.f; b3.w = 0.f; }
        float4 a0 = *(const float4*)(Ga + (size_t)(row0 + 0) * BR + k0);
        float4 a1 = *(const float4*)(Ga + (size_t)(row0 + 1) * BR + k0);
        float4 a2 = *(const float4*)(Ga + (size_t)(row0 + 2) * BR + k0);
        float4 a3 = *(const float4*)(Ga + (size_t)(row0 + 3) * BR + k0);
        FMA4(acc0, a0.x, b0); FMA4(acc0, a0.y, b1); FMA4(acc0, a0.z, b2); FMA4(acc0, a0.w, b3);
        FMA4(acc1, a1.x, b0); FMA4(acc1, a1.y, b1); FMA4(acc1, a1.z, b2); FMA4(acc1, a1.w, b3);
        FMA4(acc2, a2.x, b0); FMA4(acc2, a2.y, b1); FMA4(acc2, a2.z, b2); FMA4(acc2, a2.w, b3);
        FMA4(acc3, a3.x, b0); FMA4(acc3, a3.y, b1); FMA4(acc3, a3.z, b2); FMA4(acc3, a3.w, b3);
    }
    float* Ob = O + (size_t)row0 * BR + ct * 64 + c0;
    *(float4*)(Ob + 0 * BR) = acc0;
    *(float4*)(Ob + 1 * BR) = acc1;
    *(float4*)(Ob + 2 * BR) = acc2;
    *(float4*)(Ob + 3 * BR) = acc3;
}

// pr[m][w]. grid (16,3,9). Verified R13.
__global__ __launch_bounds__(256) void k_gops2(const float* __restrict__ E,
                                               const float* __restrict__ G,
                                               const float* __restrict__ ops1,
                                               float* __restrict__ pr) {
    int m = blockIdx.x, w = blockIdx.y, tz = blockIdx.z;
    int rt = tz / 3, ct = tz % 3;
    int A = 2 * m, C = 2 * m + 1;
    int tid = threadIdx.x;
    float dy = dy_of(E);
    const float* Asrc = ops1 + (size_t)(A * 3 + 0) * BR * BR;
    const float* Bsrc = (w == 0) ? (G + (size_t)C * BR * BR)
                                 : (ops1 + (size_t)(C * 3 + (w - 1)) * BR * BR);
    const float* Dsrc = (w == 0) ? nullptr : (ops1 + (size_t)(A * 3 + w) * BR * BR);
    float* O = pr + (size_t)(m * 3 + w) * BR * BR;
    int tx = tid & 15, ty = tid >> 4;
    int row0 = rt * 64 + ty * 4;
    int c0 = ct * 64 + tx * 4;
    float4 acc0 = {0, 0, 0, 0}, acc1 = {0, 0, 0, 0};
    float4 acc2 = {0, 0, 0, 0}, acc3 = {0, 0, 0, 0};
    for (int k0 = 0; k0 < BR; k0 += 4) {
        int e0 = C * 64 + (k0 & 63);
        float w0 = (e0 + 0 < NROWS) ? dy * E[e0 + 0] : 0.f;
        float w1 = (e0 + 1 < NROWS) ? dy * E[e0 + 1] : 0.f;
        float w2 = (e0 + 2 < NROWS) ? dy * E[e0 + 2] : 0.f;
        float w3 = (e0 + 3 < NROWS) ? dy * E[e0 + 3] : 0.f;
        const float* Bb = Bsrc + (size_t)k0 * BR + c0;
        float4 b0 = *(const float4*)(Bb + 0 * BR);
        float4 b1 = *(const float4*)(Bb + 1 * BR);
        float4 b2 = *(const float4*)(Bb + 2 * BR);
        float4 b3 = *(const float4*)(Bb + 3 * BR);
        b0.x *= w0; b0.y *= w0; b0.z *= w0; b0.w *= w0;
        b1.x *= w1; b1.y *= w1; b1.z *= w1; b1.w *= w1;
        b2.x *= w2; b2.y *= w2; b2.z *= w2; b2.w *= w2;
        b3.x *= w3; b3.y *= w3; b3.z *= w3; b3.w *= w3;
        float4 a0 = *(const float4*)(Asrc + (size_t)(row0 + 0) * BR + k0);
        float4 a1 = *(const float4*)(Asrc + (size_t)(row0 + 1) * BR + k0);
        float4 a2 = *(const float4*)(Asrc + (size_t)(row0 + 2) * BR + k0);
        float4 a3 = *(const float4*)(Asrc + (size_t)(row0 + 3) * BR + k0);
        FMA4(acc0, a0.x, b0); FMA4(acc0, a0.y, b1); FMA4(acc0, a0.z, b2); FMA4(acc0, a0.w, b3);
        FMA4(acc1, a1.x, b0); FMA4(acc1, a1.y, b1); FMA4(acc1, a1.z, b2); FMA4(acc1, a1.w, b3);
        FMA4(acc2, a2.x, b0); FMA4(acc2, a2.y, b1); FMA4(acc2, a2.z, b2); FMA4(acc2, a2.w, b3);
        FMA4(acc3, a3.x, b0); FMA4(acc3, a3.y, b1); FMA4(acc3, a3.z, b2); FMA4(acc3, a3.w, b3);
    }
    float* Ob = O + (size_t)row0 * BR + c0;
    if (Dsrc) {
        const float* Db = Dsrc + (size_t)row0 * BR + c0;
        float4 d0 = *(const float4*)(Db + 0 * BR);
        float4 d1 = *(const float4*)(Db + 1 * BR);
        float4 d2 = *(const float4*)(Db + 2 * BR);
        float4 d3 = *(const float4*)(Db + 3 * BR);
        acc0.x += d0.x; acc0.y += d0.y; acc0.z += d0.z; acc0.w += d0.w;
        acc1.x += d1.x; acc1.y += d1.y; acc1.z += d1.z; acc1.w += d1.w;
        acc2.x += d2.x; acc2.y += d2.y; acc2.z += d2.z; acc2.w += d2.w;
        acc3.x += d3.x; acc3.y += d3.y; acc3.z += d3.z; acc3.w += d3.w;
    }
    *(float4*)(Ob + 0 * BR) = acc0;
    *(float4*)(Ob + 1 * BR) = acc1;
    *(float4*)(Ob + 2 * BR) = acc2;
    *(float4*)(Ob + 3 * BR) = acc3;
}

// Cooperative cascade: all 16 pair stages in one launch, grid.sync between.
// Per stage, math/roles identical to the verified k_pair2 (R13/R17).
__global__ __launch_bounds__(512) void k_casc(const float* __restrict__ E,
                                              const float* __restrict__ K,
                                              const float* __restrict__ G,
                                              const float* __restrict__ ops1,
                                              const float* __restrict__ pr,
                                              float* __restrict__ acc,
                                              float* __restrict__ wf,
                                              float* __restrict__ out) {
    cg::grid_group gg = cg::this_grid();
    const size_t PL = (size_t)NE * NE;
    int tid = threadIdx.x;
    int bid = blockIdx.x;
    int lane = tid & 63, wv = tid >> 6;
    float dy = dy_of(E);
    __shared__ float4 vec4[4][BR / 4];

    for (int m = NPAIR - 1; m >= 0; --m) {
        int A = 2 * m, C = 2 * m + 1;
        int hasV = (m < NPAIR - 1) ? 1 : 0;

        if (bid >= 12) {
            int nJobs = (m < NPAIR - 1) ? m * 16 : 0;
            int jbase = (2 * m + 2) * BS;
            for (int job = bid - 12; job < nJobs; job += (int)gridDim.x - 12) {
                int row = job * 8 + wv;
                int j1 = jbase + lane, j2 = j1 + BS;
                float w10 = wf[0 * NE + j1], w11 = wf[1 * NE + j1], w12 = wf[2 * NE + j1];
                float w20 = 0.f, w21 = 0.f, w22 = 0.f;
                if (j2 < NROWS) {
                    w20 = wf[0 * NE + j2]; w21 = wf[1 * NE + j2]; w22 = wf[2 * NE + j2];
                }
                const float* Kb1 = K + (size_t)row * NE + j1;
                const float* Kb2 = K + (size_t)row * NE + j2;
                float s0 = Kb1[0 * PL] * w10 + Kb1[1 * PL] * w11 + Kb1[2 * PL] * w12
                         + Kb2[0 * PL] * w20 + Kb2[1 * PL] * w21 + Kb2[2 * PL] * w22;
                float s1 = Kb1[3 * PL] * w10 + Kb1[4 * PL] * w11 + Kb1[5 * PL] * w12
                         + Kb2[3 * PL] * w20 + Kb2[4 * PL] * w21 + Kb2[5 * PL] * w22;
                float s2 = Kb1[6 * PL] * w10 + Kb1[7 * PL] * w11 + Kb1[8 * PL] * w12
                         + Kb2[6 * PL] * w20 + Kb2[7 * PL] * w21 + Kb2[8 * PL] * w22;
#pragma unroll
                for (int d = 32; d; d >>= 1) {
                    s0 += __shfl_xor(s0, d);
                    s1 += __shfl_xor(s1, d);
                    s2 += __shfl_xor(s2, d);
                }
                if (lane == 0) {
                    atomicAdd(&acc[0 * NE + row], s0);
                    atomicAdd(&acc[1 * NE + row], s1);
                    atomicAdd(&acc[2 * NE + row], s2);
                }
            }
        } else {
            if (tid < BR) {
                int sp = tid >> 6, e = tid & 63;
                ((float*)vec4[0])[tid] = __hip_atomic_load(&acc[sp * NE + C * BS + e],
                                             __ATOMIC_RELAXED, __HIP_MEMORY_SCOPE_AGENT);
                ((float*)vec4[1])[tid] = __hip_atomic_load(&acc[sp * NE + A * BS + e],
                                             __ATOMIC_RELAXED, __HIP_MEMORY_SCOPE_AGENT);
                ((float*)vec4[2])[tid] = hasV ? wf[sp * NE + (2 * m + 2) * BS + e] : 0.f;
                ((float*)vec4[3])[tid] = hasV ? wf[sp * NE + (2 * m + 3) * BS + e] : 0.f;
            }
            __syncthreads();

            int rloc = tid >> 4, sub = tid & 15;
            bool isC = (bid < 6);
            int rbase = (isC ? bid : bid - 6) * 32;
            int row = rbase + rloc;
            int blk = isC ? C : A;

            const float4* m0 = (const float4*)(G + ((size_t)blk * BR + row) * BR) + sub * 3;
            const float4 *m1, *m2, *m3 = nullptr;
            const float4 *x0, *x1, *x2, *x3 = nullptr;
            if (isC) {
                m1 = (const float4*)(ops1 + ((size_t)(C * 3 + 0) * BR + row) * BR) + sub * 3;
                m2 = (const float4*)(ops1 + ((size_t)(C * 3 + 1) * BR + row) * BR) + sub * 3;
                x0 = vec4[0] + sub * 3; x1 = vec4[2] + sub * 3; x2 = vec4[3] + sub * 3;
            } else {
                m1 = (const float4*)(pr + ((size_t)(m * 3 + 0) * BR + row) * BR) + sub * 3;
                m2 = (const float4*)(pr + ((size_t)(m * 3 + 1) * BR + row) * BR) + sub * 3;
                m3 = (const float4*)(pr + ((size_t)(m * 3 + 2) * BR + row) * BR) + sub * 3;
                x0 = vec4[1] + sub * 3; x1 = vec4[0] + sub * 3;
                x2 = vec4[2] + sub * 3; x3 = vec4[3] + sub * 3;
            }
            float s = 0.f;
#pragma unroll
            for (int q = 0; q < 3; ++q) s += DOT4(m0[q], x0[q]);
            if (hasV || !isC) {
#pragma unroll
                for (int q = 0; q < 3; ++q) s += DOT4(m1[q], x1[q]);
            }
            if (hasV) {
#pragma unroll
                for (int q = 0; q < 3; ++q) s += DOT4(m2[q], x2[q]);
                if (!isC) {
#pragma unroll
                    for (int q = 0; q < 3; ++q) s += DOT4(m3[q], x3[q]);
                }
            }
            s += __shfl_xor(s, 1); s += __shfl_xor(s, 2);
            s += __shfl_xor(s, 4); s += __shfl_xor(s, 8);
            if (sub == 0) {
                int x = row >> 6, ii = row & 63;
                int i = blk * BS + ii;
                if (i < NROWS) {
                    out[(1 + x) * NE + i] = s > 0.f ? s : 0.f;
                    wf[x * NE + i] = dy * E[i] * s;
                }
            }
            __syncthreads();   // vec4 reuse safety across stages
        }
        gg.sync();
    }
}

extern "C" void kernel_launch(void* const* d_in, const int* in_sizes, int n_in,
                              void* d_out, int out_size, void* d_ws, size_t ws_size,
                              hipStream_t stream) {
    const float* E = (const float*)d_in[0];
    const float* R = (const float*)d_in[1];
    const float* K = (const float*)d_in[2];
    const float* S0 = (const float*)d_in[3];
    const float* SC = (const float*)d_in[4];
    float* out = (float*)d_out;
    float* wf = (float*)d_ws;
    float* acc = wf + 6144;
    float* Gs16 = acc + 6144;
    float* L1 = Gs16 + (size_t)128 * 48 * 48;
    float* L2 = L1 + (size_t)64 * 96 * 96;        // == G for the tail
    float* ops1 = L2 + (size_t)32 * 192 * 192;
    float* pr = ops1 + (size_t)NBLK * 3 * BR * BR;
    float* Mtmp = pr + (size_t)NPAIR * 3 * BR * BR;

    k_boot<<<136, 256, 0, stream>>>(E, R, K, S0, SC, out, wf, acc, Gs16);
    k_merge48<<<64, 256, 0, stream>>>(E, K, Gs16, L1);
    k_mA32<<<dim3(32, 9), 256, 0, stream>>>(E, K, L1, Mtmp);
    k_mB32<<<dim3(32, 36), 256, 0, stream>>>(L1, Mtmp, L2);
    k_gops1<<<dim3(NBLK, 3, 9), 256, 0, stream>>>(K, L2, ops1);
    k_gops2<<<dim3(NPAIR, 3, 9), 256, 0, stream>>>(E, L2, ops1, pr);

    void* args[] = {(void*)&E, (void*)&K, (void*)&L2, (void*)&ops1, (void*)&pr,
                    (void*)&acc, (void*)&wf, (void*)&out};
    hipLaunchCooperativeKernel((const void*)k_casc, dim3(CWG), dim3(512),
                               args, 0, stream);
}

// Round 19
// 223.852 us; speedup vs baseline: 1.8914x; 1.8914x over previous
//
#include <hip/hip_runtime.h>
#include <cstddef>
#include <cstdint>

#define NE 2048
#define NX 3
#define NROWS (NE - 1)
#define BS 64
#define BR 192
#define NBLK 32
#define NPAIR 16

// PLANAR convention: within an operator of half-energy-width he, index = x*he + e.
// ws layout (floats):
//   wf   [3*NE]        @ 0
//   acc  [3*NE]        @ 6144
//   Gs16 [128*48*48]               16-energy inverses
//   L1   [64*96*96]                32-energy inverses
//   L2   [32*192*192]              64-energy inverses  (== G for the tail)
//   ops1 [32][3][192*192]          H, J2, J3
//   pr   [16][3][192*192]          P, R2, R3
//   Mtmp [32*96*96]

static __device__ __forceinline__ float dy_of(const float* E) {
    return logf(E[NE - 1] / E[0]) / (float)(NE - 1);
}

#define DOT4(a, b) ((a).x * (b).x + (a).y * (b).y + (a).z * (b).z + (a).w * (b).w)
#define FMA4(acc, s, b) { (acc).x += (s) * (b).x; (acc).y += (s) * (b).y; \
                          (acc).z += (s) * (b).z; (acc).w += (s) * (b).w; }

// Fused boot: bid<8 -> init role (out row0, acc seed, wf[2047]); else tinv16.
__global__ __launch_bounds__(256) void k_boot(const float* __restrict__ E,
                                              const float* __restrict__ R,
                                              const float* __restrict__ K,
                                              const float* __restrict__ S0,
                                              const float* __restrict__ SC,
                                              float* __restrict__ out,
                                              float* __restrict__ wf,
                                              float* __restrict__ acc,
                                              float* __restrict__ Gs16) {
    const size_t PL = (size_t)NE * NE;
    int tid = threadIdx.x;
    float dy = dy_of(E);

    if (blockIdx.x < 8) {
        int i = blockIdx.x * 256 + tid;
        if (i >= NE) return;
        float wlast = 0.5f * dy * E[NE - 1];
        float srcl[NX], Fl[NX];
#pragma unroll
        for (int p = 0; p < NX; ++p) srcl[p] = S0[p] / R[p * NE + NE - 1];
#pragma unroll
        for (int x = 0; x < NX; ++x) {
            float s = SC[x * NE + NE - 1];
#pragma unroll
            for (int p = 0; p < NX; ++p)
                s += K[(size_t)(x * NX + p) * PL + (size_t)(NE - 1) * NE + (NE - 1)] * srcl[p];
            Fl[x] = s / R[x * NE + NE - 1];
        }
        out[i] = E[i];
        if (i == NE - 1) {
#pragma unroll
            for (int x = 0; x < NX; ++x) {
                out[(1 + x) * NE + i] = Fl[x] > 0.f ? Fl[x] : 0.f;
                wf[x * NE + i] = wlast * Fl[x];
                acc[x * NE + i] = 0.f;
            }
            return;
        }
#pragma unroll
        for (int x = 0; x < NX; ++x) {
            float s = SC[x * NE + i];
#pragma unroll
            for (int p = 0; p < NX; ++p)
                s += K[(size_t)(x * NX + p) * PL + (size_t)i * NE + (NE - 1)] *
                     (wlast * Fl[p] + srcl[p]);
            acc[x * NE + i] = s;
        }
        return;
    }

    __shared__ float4 Xs4[16][49];
    __shared__ float Kst[16][16][12];
    __shared__ float Binv[16][9];
    __shared__ float wloc[16];
    int sb = blockIdx.x - 8;
    int i0 = sb * 16;

    if (tid < 16) {
        int j = i0 + tid;
        wloc[tid] = (j < NE - 1) ? dy * E[j] : 0.f;
        int i = i0 + tid, ii = tid;
        float b00, b01, b02, b10, b11, b12, b20, b21, b22;
        if (i < NROWS) {
            float h = -0.5f * dy * E[i];
            size_t d = (size_t)i * NE + i;
            b00 = h * K[0 * PL + d] + R[0 * NE + i];
            b01 = h * K[1 * PL + d];
            b02 = h * K[2 * PL + d];
            b10 = h * K[3 * PL + d];
            b11 = h * K[4 * PL + d] + R[1 * NE + i];
            b12 = h * K[5 * PL + d];
            b20 = h * K[6 * PL + d];
            b21 = h * K[7 * PL + d];
            b22 = h * K[8 * PL + d] + R[2 * NE + i];
        } else {
            b00 = 1.f; b01 = 0.f; b02 = 0.f;
            b10 = 0.f; b11 = 1.f; b12 = 0.f;
            b20 = 0.f; b21 = 0.f; b22 = 1.f;
        }
        float C00 = b11 * b22 - b12 * b21;
        float C01 = -(b10 * b22 - b12 * b20);
        float C02 = b10 * b21 - b11 * b20;
        float C10 = -(b01 * b22 - b02 * b21);
        float C11 = b00 * b22 - b02 * b20;
        float C12 = -(b00 * b21 - b01 * b20);
        float C20 = b01 * b12 - b02 * b11;
        float C21 = -(b00 * b12 - b02 * b10);
        float C22 = b00 * b11 - b01 * b10;
        float inv = 1.f / (b00 * C00 + b01 * C01 + b02 * C02);
        Binv[ii][0] = C00 * inv; Binv[ii][1] = C10 * inv; Binv[ii][2] = C20 * inv;
        Binv[ii][3] = C01 * inv; Binv[ii][4] = C11 * inv; Binv[ii][5] = C21 * inv;
        Binv[ii][6] = C02 * inv; Binv[ii][7] = C12 * inv; Binv[ii][8] = C22 * inv;
    }
    __syncthreads();
    for (int q = tid; q < 16 * 16 * 9; q += 256) {
        int jj = q & 15;
        int ii = (q >> 4) & 15;
        int pair = q >> 8;
        Kst[ii][jj][4 * (pair / 3) + (pair % 3)] =
            K[(size_t)pair * PL + (size_t)(i0 + ii) * NE + (i0 + jj)] * wloc[jj];
    }
    __syncthreads();

    int cloc = tid >> 2, sub = tid & 3;
    if (cloc < 48) {
        for (int ii = 15; ii >= 0; --ii) {
            int i = i0 + ii;
            float v0 = 0.f, v1 = 0.f, v2 = 0.f;
            if (sub == 0) {
                v0 = (cloc == 0 * 16 + ii) ? 1.f : 0.f;
                v1 = (cloc == 1 * 16 + ii) ? 1.f : 0.f;
                v2 = (cloc == 2 * 16 + ii) ? 1.f : 0.f;
            }
            if (i < NROWS) {
                for (int jj = ii + 1 + sub; jj < 16; jj += 4) {
                    const float* kp = &Kst[ii][jj][0];
                    float4 k0 = *(const float4*)(kp);
                    float4 k1 = *(const float4*)(kp + 4);
                    float4 k2 = *(const float4*)(kp + 8);
                    float4 xv = Xs4[jj][cloc];
                    v0 += k0.x * xv.x + k0.y * xv.y + k0.z * xv.z;
                    v1 += k1.x * xv.x + k1.y * xv.y + k1.z * xv.z;
                    v2 += k2.x * xv.x + k2.y * xv.y + k2.z * xv.z;
                }
            }
            v0 += __shfl_xor(v0, 1); v0 += __shfl_xor(v0, 2);
            v1 += __shfl_xor(v1, 1); v1 += __shfl_xor(v1, 2);
            v2 += __shfl_xor(v2, 1); v2 += __shfl_xor(v2, 2);
            if (sub == 0) {
                float f0, f1, f2;
                if (i < NROWS) {
                    const float* bv = Binv[ii];
                    f0 = bv[0] * v0 + bv[1] * v1 + bv[2] * v2;
                    f1 = bv[3] * v0 + bv[4] * v1 + bv[5] * v2;
                    f2 = bv[6] * v0 + bv[7] * v1 + bv[8] * v2;
                } else {
                    f0 = v0; f1 = v1; f2 = v2;
                }
                Xs4[ii][cloc] = make_float4(f0, f1, f2, 0.f);
            }
            __builtin_amdgcn_wave_barrier();
        }
    }
    __syncthreads();
    float* Gb = Gs16 + (size_t)sb * 48 * 48;
    for (int t = tid; t < 48 * 48; t += 256) {
        int rp = t / 48, c = t % 48;
        int x = rp >> 4, ii = rp & 15;
        Gb[t] = ((const float*)&Xs4[ii][c])[x];
    }
}

// Merge 16+16 -> 32 (verified). 64 WGs.
__global__ __launch_bounds__(256) void k_merge48(const float* __restrict__ E,
                                                 const float* __restrict__ K,
                                                 const float* __restrict__ Gs16,
                                                 float* __restrict__ G32) {
    __shared__ float Ls[48][49], Bs[48][49], Ks[48][49], Ms[48][49];
    const size_t PL = (size_t)NE * NE;
    int q = blockIdx.x;
    int i0 = q * 32;
    int tid = threadIdx.x;
    float dy = dy_of(E);
    const float* GL = Gs16 + (size_t)(2 * q) * 2304;
    const float* GH = Gs16 + (size_t)(2 * q + 1) * 2304;
    for (int t = tid; t < 2304; t += 256) {
        int r = t / 48, c = t % 48;
        Ls[r][c] = GL[t];
        Bs[r][c] = GH[t];
        int x = r >> 4, ii = r & 15, p = c >> 4, jj = c & 15;
        int j = i0 + 16 + jj;
        float w = (j < NE - 1) ? dy * E[j] : 0.f;
        Ks[r][c] = w * K[(size_t)(x * 3 + p) * PL + (size_t)(i0 + ii) * NE + j];
    }
    __syncthreads();
    int tx = tid & 15, ty = tid >> 4;
    float m[3][3] = {};
    for (int k = 0; k < 48; ++k) {
        float a0 = Ks[ty * 3 + 0][k], a1 = Ks[ty * 3 + 1][k], a2 = Ks[ty * 3 + 2][k];
        float b0 = Bs[k][tx * 3 + 0], b1 = Bs[k][tx * 3 + 1], b2 = Bs[k][tx * 3 + 2];
        m[0][0] += a0 * b0; m[0][1] += a0 * b1; m[0][2] += a0 * b2;
        m[1][0] += a1 * b0; m[1][1] += a1 * b1; m[1][2] += a1 * b2;
        m[2][0] += a2 * b0; m[2][1] += a2 * b1; m[2][2] += a2 * b2;
    }
#pragma unroll
    for (int i = 0; i < 3; ++i)
#pragma unroll
        for (int j = 0; j < 3; ++j) Ms[ty * 3 + i][tx * 3 + j] = m[i][j];
    __syncthreads();
    float cc[3][3] = {};
    for (int k = 0; k < 48; ++k) {
        float a0 = Ls[ty * 3 + 0][k], a1 = Ls[ty * 3 + 1][k], a2 = Ls[ty * 3 + 2][k];
        float b0 = Ms[k][tx * 3 + 0], b1 = Ms[k][tx * 3 + 1], b2 = Ms[k][tx * 3 + 2];
        cc[0][0] += a0 * b0; cc[0][1] += a0 * b1; cc[0][2] += a0 * b2;
        cc[1][0] += a1 * b0; cc[1][1] += a1 * b1; cc[1][2] += a1 * b2;
        cc[2][0] += a2 * b0; cc[2][1] += a2 * b1; cc[2][2] += a2 * b2;
    }
    float* O = G32 + (size_t)q * 96 * 96;
    for (int t = tid; t < 2304; t += 256) {
        int r = t / 48, c = t % 48;
        int x = r >> 4, ii = r & 15, p = c >> 4, jj = c & 15;
        O[(size_t)(x * 32 + ii) * 96 + (p * 32 + jj)] = Ls[r][c];
        O[(size_t)(x * 32 + 16 + ii) * 96 + (p * 32 + 16 + jj)] = Bs[r][c];
        O[(size_t)(x * 32 + 16 + ii) * 96 + (p * 32 + jj)] = 0.f;
    }
#pragma unroll
    for (int i = 0; i < 3; ++i)
#pragma unroll
        for (int j = 0; j < 3; ++j) {
            int r = ty * 3 + i, c = tx * 3 + j;
            int x = r >> 4, ii = r & 15, p = c >> 4, jj = c & 15;
            O[(size_t)(x * 32 + ii) * 96 + (p * 32 + 16 + jj)] = cc[i][j];
        }
}

// LDS-free merge A (he=32, h=96). grid (32,9). Verified R16/R17.
__global__ __launch_bounds__(256) void k_mA32(const float* __restrict__ E,
                                              const float* __restrict__ K,
                                              const float* __restrict__ srcG,
                                              float* __restrict__ M) {
    const size_t PL = (size_t)NE * NE;
    const int h = 96, he = 32;
    int mg = blockIdx.x, tz = blockIdx.y;
    int tr = tz / 3, tc = tz % 3;
    int tid = threadIdx.x;
    int tx = tid & 15, ty = tid >> 4;
    int i0 = mg * 64;
    int row0 = tr * 32 + ty * 2;
    int c0 = tc * 32 + tx * 2;
    float dy = dy_of(E);
    const float* GH = srcG + (size_t)(2 * mg + 1) * h * h;
    int xr = row0 / he, er = row0 % he;
    float2 acc0 = {0, 0}, acc1 = {0, 0};
    for (int k0 = 0; k0 < h; k0 += 4) {
        int p = k0 / he, ek = k0 % he;
        int j0 = i0 + he + ek;
        float w0 = (j0 + 0 < NE - 1) ? dy * E[j0 + 0] : 0.f;
        float w1 = (j0 + 1 < NE - 1) ? dy * E[j0 + 1] : 0.f;
        float w2 = (j0 + 2 < NE - 1) ? dy * E[j0 + 2] : 0.f;
        float w3 = (j0 + 3 < NE - 1) ? dy * E[j0 + 3] : 0.f;
        const float* Kp = K + (size_t)(xr * 3 + p) * PL + (size_t)(i0 + er) * NE + j0;
        float4 a0 = *(const float4*)(Kp);
        float4 a1 = *(const float4*)(Kp + NE);
        a0.x *= w0; a0.y *= w1; a0.z *= w2; a0.w *= w3;
        a1.x *= w0; a1.y *= w1; a1.z *= w2; a1.w *= w3;
        float2 b0 = *(const float2*)(GH + (size_t)(k0 + 0) * h + c0);
        float2 b1 = *(const float2*)(GH + (size_t)(k0 + 1) * h + c0);
        float2 b2 = *(const float2*)(GH + (size_t)(k0 + 2) * h + c0);
        float2 b3 = *(const float2*)(GH + (size_t)(k0 + 3) * h + c0);
        acc0.x += a0.x * b0.x + a0.y * b1.x + a0.z * b2.x + a0.w * b3.x;
        acc0.y += a0.x * b0.y + a0.y * b1.y + a0.z * b2.y + a0.w * b3.y;
        acc1.x += a1.x * b0.x + a1.y * b1.x + a1.z * b2.x + a1.w * b3.x;
        acc1.y += a1.x * b0.y + a1.y * b1.y + a1.z * b2.y + a1.w * b3.y;
    }
    float* Ob = M + (size_t)mg * h * h + (size_t)row0 * h + c0;
    *(float2*)(Ob) = acc0;
    *(float2*)(Ob + h) = acc1;
}

// LDS-free merge B (he=32, n=192). grid (32,36). Verified R16/R17.
__global__ __launch_bounds__(256) void k_mB32(const float* __restrict__ srcG,
                                              const float* __restrict__ M,
                                              float* __restrict__ dst) {
    const int h = 96, n = 192;
    int mg = blockIdx.x, tz = blockIdx.y;
    int tr = tz / 6, tc = tz % 6;
    int tid = threadIdx.x;
    int tx = tid & 15, ty = tid >> 4;
    int row0 = tr * 32 + ty * 2;
    int c0 = tc * 32 + tx * 2;
    const float* GL = srcG + (size_t)(2 * mg) * h * h;
    const float* GH = srcG + (size_t)(2 * mg + 1) * h * h;
    const float* Mb = M + (size_t)mg * h * h;
    float* O = dst + (size_t)mg * n * n;
    int xr = row0 / 64, e2r = row0 % 64;
    int xc = c0 / 64, e2c = c0 % 64;
    bool rtop = e2r < 32, ctop = e2c < 32;
    if (rtop && ctop) {
        const float* S = GL + (size_t)(xr * 32 + e2r) * h + (xc * 32 + e2c);
        *(float2*)(O + (size_t)row0 * n + c0) = *(const float2*)(S);
        *(float2*)(O + (size_t)(row0 + 1) * n + c0) = *(const float2*)(S + h);
    } else if (!rtop && !ctop) {
        const float* S = GH + (size_t)(xr * 32 + e2r - 32) * h + (xc * 32 + e2c - 32);
        *(float2*)(O + (size_t)row0 * n + c0) = *(const float2*)(S);
        *(float2*)(O + (size_t)(row0 + 1) * n + c0) = *(const float2*)(S + h);
    } else if (!rtop && ctop) {
        float2 z = {0, 0};
        *(float2*)(O + (size_t)row0 * n + c0) = z;
        *(float2*)(O + (size_t)(row0 + 1) * n + c0) = z;
    } else {
        const float* Ar = GL + (size_t)(xr * 32 + e2r) * h;
        int cm = xc * 32 + (e2c - 32);
        float2 acc0 = {0, 0}, acc1 = {0, 0};
        for (int k0 = 0; k0 < h; k0 += 4) {
            float4 a0 = *(const float4*)(Ar + k0);
            float4 a1 = *(const float4*)(Ar + h + k0);
            float2 b0 = *(const float2*)(Mb + (size_t)(k0 + 0) * h + cm);
            float2 b1 = *(const float2*)(Mb + (size_t)(k0 + 1) * h + cm);
            float2 b2 = *(const float2*)(Mb + (size_t)(k0 + 2) * h + cm);
            float2 b3 = *(const float2*)(Mb + (size_t)(k0 + 3) * h + cm);
            acc0.x += a0.x * b0.x + a0.y * b1.x + a0.z * b2.x + a0.w * b3.x;
            acc0.y += a0.x * b0.y + a0.y * b1.y + a0.z * b2.y + a0.w * b3.y;
            acc1.x += a1.x * b0.x + a1.y * b1.x + a1.z * b2.x + a1.w * b3.x;
            acc1.y += a1.x * b0.y + a1.y * b1.y + a1.z * b2.y + a1.w * b3.y;
        }
        *(float2*)(O + (size_t)row0 * n + c0) = acc0;
        *(float2*)(O + (size_t)(row0 + 1) * n + c0) = acc1;
    }
}

// ops1[s][t-1] = G[s] @ Kp(s,s+t). grid (32,3,9). Verified R13.
__global__ __launch_bounds__(256) void k_gops1(const float* __restrict__ K,
                                               const float* __restrict__ G,
                                               float* __restrict__ ops1) {
    int s = blockIdx.x, ty_ = blockIdx.y, tz = blockIdx.z;
    int rt = tz / 3, ct = tz % 3;
    int t = ty_ + 1;
    float* O = ops1 + (size_t)(s * 3 + ty_) * BR * BR;
    int tid = threadIdx.x;
    if (s + t > NBLK - 1) {
        for (int q = tid; q < 64 * 64; q += 256)
            O[(size_t)(rt * 64 + q / 64) * BR + ct * 64 + (q % 64)] = 0.f;
        return;
    }
    const size_t PL = (size_t)NE * NE;
    const float* Ga = G + (size_t)s * BR * BR;
    int tgt0 = (s + t) * 64;
    int tx = tid & 15, ty = tid >> 4;
    int row0 = rt * 64 + ty * 4;
    int c0 = tx * 4;
    bool maskLast = (s + t == NBLK - 1) && (tx == 15);
    float4 acc0 = {0, 0, 0, 0}, acc1 = {0, 0, 0, 0};
    float4 acc2 = {0, 0, 0, 0}, acc3 = {0, 0, 0, 0};
    for (int k0 = 0; k0 < BR; k0 += 4) {
        int x = k0 >> 6;
        const float* Bb = K + (size_t)(x * 3 + ct) * PL +
                          (size_t)(s * 64 + (k0 & 63)) * NE + tgt0 + c0;
        float4 b0 = *(const float4*)(Bb);
        float4 b1 = *(const float4*)(Bb + NE);
        float4 b2 = *(const float4*)(Bb + 2 * NE);
        float4 b3 = *(const float4*)(Bb + 3 * NE);
        if (maskLast) { b0.w = 0.f; b1.w = 0.f; b2.w = 0.f; b3.w = 0.f; }
        float4 a0 = *(const float4*)(Ga + (size_t)(row0 + 0) * BR + k0);
        float4 a1 = *(const float4*)(Ga + (size_t)(row0 + 1) * BR + k0);
        float4 a2 = *(const float4*)(Ga + (size_t)(row0 + 2) * BR + k0);
        float4 a3 = *(const float4*)(Ga + (size_t)(row0 + 3) * BR + k0);
        FMA4(acc0, a0.x, b0); FMA4(acc0, a0.y, b1); FMA4(acc0, a0.z, b2); FMA4(acc0, a0.w, b3);
        FMA4(acc1, a1.x, b0); FMA4(acc1, a1.y, b1); FMA4(acc1, a1.z, b2); FMA4(acc1, a1.w, b3);
        FMA4(acc2, a2.x, b0); FMA4(acc2, a2.y, b1); FMA4(acc2, a2.z, b2); FMA4(acc2, a2.w, b3);
        FMA4(acc3, a3.x, b0); FMA4(acc3, a3.y, b1); FMA4(acc3, a3.z, b2); FMA4(acc3, a3.w, b3);
    }
    float* Ob = O + (size_t)row0 * BR + ct * 64 + c0;
    *(float4*)(Ob + 0 * BR) = acc0;
    *(float4*)(Ob + 1 * BR) = acc1;
    *(float4*)(Ob + 2 * BR) = acc2;
    *(float4*)(Ob + 3 * BR) = acc3;
}

// pr[m][w]. grid (16,3,9). Verified R13.
__global__ __launch_bounds__(256) void k_gops2(const float* __restrict__ E,
                                               const float* __restrict__ G,
                                               const float* __restrict__ ops1,
                                               float* __restrict__ pr) {
    int m = blockIdx.x, w = blockIdx.y, tz = blockIdx.z;
    int rt = tz / 3, ct = tz % 3;
    int A = 2 * m, C = 2 * m + 1;
    int tid = threadIdx.x;
    float dy = dy_of(E);
    const float* Asrc = ops1 + (size_t)(A * 3 + 0) * BR * BR;
    const float* Bsrc = (w == 0) ? (G + (size_t)C * BR * BR)
                                 : (ops1 + (size_t)(C * 3 + (w - 1)) * BR * BR);
    const float* Dsrc = (w == 0) ? nullptr : (ops1 + (size_t)(A * 3 + w) * BR * BR);
    float* O = pr + (size_t)(m * 3 + w) * BR * BR;
    int tx = tid & 15, ty = tid >> 4;
    int row0 = rt * 64 + ty * 4;
    int c0 = ct * 64 + tx * 4;
    float4 acc0 = {0, 0, 0, 0}, acc1 = {0, 0, 0, 0};
    float4 acc2 = {0, 0, 0, 0}, acc3 = {0, 0, 0, 0};
    for (int k0 = 0; k0 < BR; k0 += 4) {
        int e0 = C * 64 + (k0 & 63);
        float w0 = (e0 + 0 < NROWS) ? dy * E[e0 + 0] : 0.f;
        float w1 = (e0 + 1 < NROWS) ? dy * E[e0 + 1] : 0.f;
        float w2 = (e0 + 2 < NROWS) ? dy * E[e0 + 2] : 0.f;
        float w3 = (e0 + 3 < NROWS) ? dy * E[e0 + 3] : 0.f;
        const float* Bb = Bsrc + (size_t)k0 * BR + c0;
        float4 b0 = *(const float4*)(Bb + 0 * BR);
        float4 b1 = *(const float4*)(Bb + 1 * BR);
        float4 b2 = *(const float4*)(Bb + 2 * BR);
        float4 b3 = *(const float4*)(Bb + 3 * BR);
        b0.x *= w0; b0.y *= w0; b0.z *= w0; b0.w *= w0;
        b1.x *= w1; b1.y *= w1; b1.z *= w1; b1.w *= w1;
        b2.x *= w2; b2.y *= w2; b2.z *= w2; b2.w *= w2;
        b3.x *= w3; b3.y *= w3; b3.z *= w3; b3.w *= w3;
        float4 a0 = *(const float4*)(Asrc + (size_t)(row0 + 0) * BR + k0);
        float4 a1 = *(const float4*)(Asrc + (size_t)(row0 + 1) * BR + k0);
        float4 a2 = *(const float4*)(Asrc + (size_t)(row0 + 2) * BR + k0);
        float4 a3 = *(const float4*)(Asrc + (size_t)(row0 + 3) * BR + k0);
        FMA4(acc0, a0.x, b0); FMA4(acc0, a0.y, b1); FMA4(acc0, a0.z, b2); FMA4(acc0, a0.w, b3);
        FMA4(acc1, a1.x, b0); FMA4(acc1, a1.y, b1); FMA4(acc1, a1.z, b2); FMA4(acc1, a1.w, b3);
        FMA4(acc2, a2.x, b0); FMA4(acc2, a2.y, b1); FMA4(acc2, a2.z, b2); FMA4(acc2, a2.w, b3);
        FMA4(acc3, a3.x, b0); FMA4(acc3, a3.y, b1); FMA4(acc3, a3.z, b2); FMA4(acc3, a3.w, b3);
    }
    float* Ob = O + (size_t)row0 * BR + c0;
    if (Dsrc) {
        const float* Db = Dsrc + (size_t)row0 * BR + c0;
        float4 d0 = *(const float4*)(Db + 0 * BR);
        float4 d1 = *(const float4*)(Db + 1 * BR);
        float4 d2 = *(const float4*)(Db + 2 * BR);
        float4 d3 = *(const float4*)(Db + 3 * BR);
        acc0.x += d0.x; acc0.y += d0.y; acc0.z += d0.z; acc0.w += d0.w;
        acc1.x += d1.x; acc1.y += d1.y; acc1.z += d1.z; acc1.w += d1.w;
        acc2.x += d2.x; acc2.y += d2.y; acc2.z += d2.z; acc2.w += d2.w;
        acc3.x += d3.x; acc3.y += d3.y; acc3.z += d3.z; acc3.w += d3.w;
    }
    *(float4*)(Ob + 0 * BR) = acc0;
    *(float4*)(Ob + 1 * BR) = acc1;
    *(float4*)(Ob + 2 * BR) = acc2;
    *(float4*)(Ob + 3 * BR) = acc3;
}

// Pair stage (no intra-kernel deps). Verified R13/R17.
__global__ __launch_bounds__(512) void k_pair2(const float* __restrict__ E,
                                               const float* __restrict__ K,
                                               const float* __restrict__ G,
                                               const float* __restrict__ ops1,
                                               const float* __restrict__ pr,
                                               float* __restrict__ acc,
                                               float* __restrict__ wf,
                                               float* __restrict__ out,
                                               int m, int hasV) {
    const size_t PL = (size_t)NE * NE;
    int A = 2 * m, C = 2 * m + 1;
    int tid = threadIdx.x;
    int bid = blockIdx.x;
    int lane = tid & 63, wv = tid >> 6;

    if (bid >= 12) {
        int jbase = (2 * m + 2) * BS;
        int row = (bid - 12) * 8 + wv;
        int j1 = jbase + lane, j2 = j1 + BS;
        float w10 = wf[0 * NE + j1], w11 = wf[1 * NE + j1], w12 = wf[2 * NE + j1];
        float w20 = 0.f, w21 = 0.f, w22 = 0.f;
        if (j2 < NROWS) {
            w20 = wf[0 * NE + j2]; w21 = wf[1 * NE + j2]; w22 = wf[2 * NE + j2];
        }
        const float* Kb1 = K + (size_t)row * NE + j1;
        const float* Kb2 = K + (size_t)row * NE + j2;
        float s0 = Kb1[0 * PL] * w10 + Kb1[1 * PL] * w11 + Kb1[2 * PL] * w12
                 + Kb2[0 * PL] * w20 + Kb2[1 * PL] * w21 + Kb2[2 * PL] * w22;
        float s1 = Kb1[3 * PL] * w10 + Kb1[4 * PL] * w11 + Kb1[5 * PL] * w12
                 + Kb2[3 * PL] * w20 + Kb2[4 * PL] * w21 + Kb2[5 * PL] * w22;
        float s2 = Kb1[6 * PL] * w10 + Kb1[7 * PL] * w11 + Kb1[8 * PL] * w12
                 + Kb2[6 * PL] * w20 + Kb2[7 * PL] * w21 + Kb2[8 * PL] * w22;
#pragma unroll
        for (int d = 32; d; d >>= 1) {
            s0 += __shfl_xor(s0, d);
            s1 += __shfl_xor(s1, d);
            s2 += __shfl_xor(s2, d);
        }
        if (lane == 0) {
            atomicAdd(&acc[0 * NE + row], s0);
            atomicAdd(&acc[1 * NE + row], s1);
            atomicAdd(&acc[2 * NE + row], s2);
        }
        return;
    }

    __shared__ float4 vec4[4][BR / 4];        // aC, aA, v2, v3
    float dy = dy_of(E);
    if (tid < BR) {
        int sp = tid >> 6, e = tid & 63;
        ((float*)vec4[0])[tid] = __hip_atomic_load(&acc[sp * NE + C * BS + e],
                                     __ATOMIC_RELAXED, __HIP_MEMORY_SCOPE_AGENT);
        ((float*)vec4[1])[tid] = __hip_atomic_load(&acc[sp * NE + A * BS + e],
                                     __ATOMIC_RELAXED, __HIP_MEMORY_SCOPE_AGENT);
        ((float*)vec4[2])[tid] = hasV ? wf[sp * NE + (2 * m + 2) * BS + e] : 0.f;
        ((float*)vec4[3])[tid] = hasV ? wf[sp * NE + (2 * m + 3) * BS + e] : 0.f;
    }
    __syncthreads();

    int rloc = tid >> 4, sub = tid & 15;
    bool isC = (bid < 6);
    int rbase = (isC ? bid : bid - 6) * 32;
    int row = rbase + rloc;
    int blk = isC ? C : A;

    const float4* m0 = (const float4*)(G + ((size_t)blk * BR + row) * BR) + sub * 3;
    const float4 *m1, *m2, *m3 = nullptr;
    const float4 *x0, *x1, *x2, *x3 = nullptr;
    if (isC) {
        m1 = (const float4*)(ops1 + ((size_t)(C * 3 + 0) * BR + row) * BR) + sub * 3;
        m2 = (const float4*)(ops1 + ((size_t)(C * 3 + 1) * BR + row) * BR) + sub * 3;
        x0 = vec4[0] + sub * 3; x1 = vec4[2] + sub * 3; x2 = vec4[3] + sub * 3;
    } else {
        m1 = (const float4*)(pr + ((size_t)(m * 3 + 0) * BR + row) * BR) + sub * 3;
        m2 = (const float4*)(pr + ((size_t)(m * 3 + 1) * BR + row) * BR) + sub * 3;
        m3 = (const float4*)(pr + ((size_t)(m * 3 + 2) * BR + row) * BR) + sub * 3;
        x0 = vec4[1] + sub * 3; x1 = vec4[0] + sub * 3;
        x2 = vec4[2] + sub * 3; x3 = vec4[3] + sub * 3;
    }
    float s = 0.f;
#pragma unroll
    for (int q = 0; q < 3; ++q) s += DOT4(m0[q], x0[q]);
    if (hasV || !isC) {
#pragma unroll
        for (int q = 0; q < 3; ++q) s += DOT4(m1[q], x1[q]);
    }
    if (hasV) {
#pragma unroll
        for (int q = 0; q < 3; ++q) s += DOT4(m2[q], x2[q]);
        if (!isC) {
#pragma unroll
            for (int q = 0; q < 3; ++q) s += DOT4(m3[q], x3[q]);
        }
    }
    s += __shfl_xor(s, 1); s += __shfl_xor(s, 2);
    s += __shfl_xor(s, 4); s += __shfl_xor(s, 8);
    if (sub == 0) {
        int x = row >> 6, ii = row & 63;
        int i = blk * BS + ii;
        if (i < NROWS) {
            out[(1 + x) * NE + i] = s > 0.f ? s : 0.f;
            wf[x * NE + i] = dy * E[i] * s;
        }
    }
}

extern "C" void kernel_launch(void* const* d_in, const int* in_sizes, int n_in,
                              void* d_out, int out_size, void* d_ws, size_t ws_size,
                              hipStream_t stream) {
    const float* E = (const float*)d_in[0];
    const float* R = (const float*)d_in[1];
    const float* K = (const float*)d_in[2];
    const float* S0 = (const float*)d_in[3];
    const float* SC = (const float*)d_in[4];
    float* out = (float*)d_out;
    float* wf = (float*)d_ws;
    float* acc = wf + 6144;
    float* Gs16 = acc + 6144;
    float* L1 = Gs16 + (size_t)128 * 48 * 48;
    float* L2 = L1 + (size_t)64 * 96 * 96;        // == G for the tail
    float* ops1 = L2 + (size_t)32 * 192 * 192;
    float* pr = ops1 + (size_t)NBLK * 3 * BR * BR;
    float* Mtmp = pr + (size_t)NPAIR * 3 * BR * BR;

    k_boot<<<136, 256, 0, stream>>>(E, R, K, S0, SC, out, wf, acc, Gs16);
    k_merge48<<<64, 256, 0, stream>>>(E, K, Gs16, L1);
    k_mA32<<<dim3(32, 9), 256, 0, stream>>>(E, K, L1, Mtmp);
    k_mB32<<<dim3(32, 36), 256, 0, stream>>>(L1, Mtmp, L2);
    k_gops1<<<dim3(NBLK, 3, 9), 256, 0, stream>>>(K, L2, ops1);
    k_gops2<<<dim3(NPAIR, 3, 9), 256, 0, stream>>>(E, L2, ops1, pr);

    for (int m = NPAIR - 1; m >= 0; --m) {
        int nFar = (m < NPAIR - 1) ? m * 16 : 0;
        int hasV = (m < NPAIR - 1) ? 1 : 0;
        k_pair2<<<12 + nFar, 512, 0, stream>>>(E, K, L2, ops1, pr, acc, wf, out,
                                               m, hasV);
    }
}